// Round 6
// baseline (1465.480 us; speedup 1.0000x reference)
//
#include <hip/hip_runtime.h>
#include <math.h>

// Soft-DTW (gamma=0.1), 4096x4096, wave-parallel band pipeline v4.
// 16 WGs x 4 waves (256 thr, 1 wave/SIMD). Band = 4g+w, lane l = row band*64+l;
// lane l at step t computes cell (row, t-l). Scaled log2 domain R' = R/(g*ln2).
// v4 vs v3: (1) NO s_sleep in polls -- tight load-spin (s_sleep parked waves
// ~5us/miss, the 47k-cy/hop mystery); (2) validate-AHEAD: at chunk c the
// consumer validates chunk c+1 and computes from already-validated c, so
// steady-state polls succeed first try (deterministic ~95-step lag, no
// ratchet); (3) 1 wave/SIMD (no issue contention); producer burst-writes at
// chunk end. Handoffs: 48 intra-WG via LDS rows, 15 inter-WG via ws (relaxed
// agent atomics, value-as-flag vs 0xAA poison).

#define KS     14.426950408889634f   // 1/(0.1*ln2)
#define BIGP   1.4426950e+11f        // 1e10 * KS
#define NN     4096
#define POISON 0xAAAAAAAAu           // harness ws poison / our LDS sentinel
#define YPADF  64
#define YPADB  192
#define YTOT   (YPADF + NN + YPADB)  // 4352 floats
#define NWAVE  4
#define NWG    16

__device__ __forceinline__ float dpp_shr1(float oldv, float src) {
    // lanes 1..63 <- src[lane-1]; lane 0 keeps oldv (bound_ctrl=false)
    int o = __float_as_int(oldv), s = __float_as_int(src);
    return __int_as_float(__builtin_amdgcn_update_dpp(o, s, 0x138 /*wave_shr:1*/, 0xF, 0xF, false));
}
__device__ __forceinline__ float rdlane(float v, int l) {
    return __int_as_float(__builtin_amdgcn_readlane(__float_as_int(v), l));
}

__global__ __launch_bounds__(256, 1)
void sdtw_kernel(const float* __restrict__ x, const float* __restrict__ y,
                 float* __restrict__ out, float* __restrict__ bndG) {
    __shared__ float    shy[YTOT];            // y*sqrt(K), zero-padded
    __shared__ unsigned shb[NWAVE - 1][NN];   // 48 KiB intra-WG boundary rows
    const int g = blockIdx.x, tid = threadIdx.x;
    const int w = tid >> 6, lane = tid & 63;
    const int band = g * NWAVE + w;
    const float sqK = sqrtf(KS);

    for (int i = tid; i < (NWAVE - 1) * NN; i += 256) (&shb[0][0])[i] = POISON;
    for (int i = tid; i < YTOT; i += 256) {
        int yi = i - YPADF;
        shy[i] = (yi >= 0 && yi < NN) ? y[yi] * sqK : 0.0f;
    }
    __syncthreads();

    const float xs = x[band * 64 + lane] * sqK;
    const bool consL = (w > 0), consG = (w == 0 && g > 0);
    const bool prodL = (w < NWAVE - 1), prodG = (w == NWAVE - 1 && g < NWG - 1);
    unsigned*                loutU = &shb[prodL ? w : 0][0];
    const volatile unsigned* linU  = &shb[consL ? w - 1 : 0][0];
    unsigned*       goutU = (unsigned*)(bndG + g * NN);
    const unsigned* ginU  = (const unsigned*)(bndG + (g > 0 ? g - 1 : 0) * NN);

    float r1  = BIGP;                                   // own R' at t-1
    float vdg = (band == 0 && lane == 0) ? 0.0f : BIGP; // diag source
    float rsave = 0.0f;
    float yw[16], ywn[16];
    float bcur = 0.0f, bnx = 0.0f;
    const int myi = lane & 15;

    // ---- prime: y window chunk 0; validate boundary chunk 0 ---------------
    #pragma unroll
    for (int k = 0; k < 16; ++k) yw[k] = shy[YPADF + k - lane];
    if (consL) {
        unsigned u; int bail = 0;
        do { u = linU[myi]; } while (!__all(u != POISON) && ++bail < (1 << 22));
        bcur = __uint_as_float(u);
    } else if (consG) {
        unsigned u; int bail = 0;
        do { u = __hip_atomic_load(&ginU[myi], __ATOMIC_RELAXED, __HIP_MEMORY_SCOPE_AGENT); }
        while (!__all(u != POISON) && ++bail < (1 << 22));
        bcur = __uint_as_float(u);
    }

    for (int c = 0; c < 260; ++c) {                     // 260*16 = 4160 steps
        const int base = c * 16;
        // ---- validate NEXT chunk (c+1): steady-state = first-try success --
        if (c + 1 <= 255) {
            const int li = base + 16 + myi;
            if (consL) {
                unsigned u; int bail = 0;
                do { u = linU[li]; } while (!__all(u != POISON) && ++bail < (1 << 22));
                bnx = __uint_as_float(u);
            } else if (consG) {
                unsigned u; int bail = 0;
                do { u = __hip_atomic_load(&ginU[li], __ATOMIC_RELAXED, __HIP_MEMORY_SCOPE_AGENT); }
                while (!__all(u != POISON) && ++bail < (1 << 22));
                bnx = __uint_as_float(u);
            }
        }
        // ---- y window prefetch for next chunk -----------------------------
        {
            const float* yb = shy + YPADF + base + 16 - lane;
            #pragma unroll
            for (int k = 0; k < 16; ++k) ywn[k] = yb[k];
        }
        // ---- 16 DP steps --------------------------------------------------
        float rsv[16];
        #pragma unroll
        for (int s = 0; s < 16; ++s) {
            float binj = (consL || consG) ? rdlane(bcur, s) : BIGP;
            float vup  = dpp_shr1(binj, r1);            // R'[i-1][j]
            float m    = fminf(fminf(vup, vdg), r1);    // min3
            float e1 = __builtin_amdgcn_exp2f(m - vup);
            float e3 = __builtin_amdgcn_exp2f(m - vdg);
            float e2 = __builtin_amdgcn_exp2f(m - r1);
            float lg = __builtin_amdgcn_logf((e1 + e3) + e2);   // log2
            float diff = xs - yw[s];
            float rn = fmaf(diff, diff, m) - lg;        // d' + softmin'
            vdg = vup; r1 = rn; rsv[s] = rn;
        }
        if (c == 259) rsave = rsv[14];                  // t=4158: R'[4095][4095]
        // ---- producer burst (off hot path, lane 63 only) ------------------
        if (lane == 63 && (prodL || prodG)) {
            #pragma unroll
            for (int s = 0; s < 16; ++s) {
                const int j = base + s - 63;
                if (j >= 0 && j < NN) {
                    if (prodL) *(volatile unsigned*)&loutU[j] = __float_as_uint(rsv[s]);
                    else __hip_atomic_store(&goutU[j], __float_as_uint(rsv[s]),
                                            __ATOMIC_RELAXED, __HIP_MEMORY_SCOPE_AGENT);
                }
            }
        }
        // ---- rotate -------------------------------------------------------
        bcur = bnx;
        #pragma unroll
        for (int k = 0; k < 16; ++k) yw[k] = ywn[k];
    }

    if (band == 63 && lane == 63)
        out[0] = fabsf(rsave * (1.0f / KS));
}

extern "C" void kernel_launch(void* const* d_in, const int* in_sizes, int n_in,
                              void* d_out, int out_size, void* d_ws, size_t ws_size,
                              hipStream_t stream) {
    const float* x = (const float*)d_in[0];   // "inputs"  (rows)
    const float* y = (const float*)d_in[1];   // "targets" (cols)
    float* out = (float*)d_out;
    float* bndG = (float*)d_ws;               // 15 used rows * 16 KiB = 240 KiB
    sdtw_kernel<<<dim3(NWG), dim3(256), 0, stream>>>(x, y, out, bndG);
}